// Round 6
// baseline (254.375 us; speedup 1.0000x reference)
//
#include <hip/hip_runtime.h>
#include <math.h>

constexpr int T_TOK = 16384;
constexpr int HDIM  = 2048;
constexpr int NEXP  = 64;
constexpr int TPB   = 32;            // tokens per block -> grid 512, 2 blocks/CU
constexpr int KSTEP = 64;
constexpr int NK    = HDIM / KSTEP;  // 32 k-iterations

typedef __attribute__((ext_vector_type(8))) short v8s;   // 8 bf16 (4 VGPRs)
typedef __attribute__((ext_vector_type(4))) float v4f;   // 4 fp32 acc

#define MFMA_BF16 __builtin_amdgcn_mfma_f32_16x16x32_bf16

// Dekker-style truncation split: x = h + m + l exactly to ~24 mantissa bits.
static __device__ __forceinline__ void split3(float x, unsigned short& h,
                                              unsigned short& m, unsigned short& l)
{
    unsigned u0 = __float_as_uint(x);
    h = (unsigned short)(u0 >> 16);
    float r1 = x - __uint_as_float(u0 & 0xFFFF0000u);     // exact
    unsigned u1 = __float_as_uint(r1);
    m = (unsigned short)(u1 >> 16);
    float r2 = r1 - __uint_as_float(u1 & 0xFFFF0000u);    // exact
    l = (unsigned short)(__float_as_uint(r2) >> 16);
}

static __device__ __forceinline__ void frag3(const float4& x0, const float4& x1,
                                             v8s& h, v8s& m, v8s& l)
{
    unsigned short sh, sm, sl;
    split3(x0.x, sh, sm, sl); h[0]=(short)sh; m[0]=(short)sm; l[0]=(short)sl;
    split3(x0.y, sh, sm, sl); h[1]=(short)sh; m[1]=(short)sm; l[1]=(short)sl;
    split3(x0.z, sh, sm, sl); h[2]=(short)sh; m[2]=(short)sm; l[2]=(short)sl;
    split3(x0.w, sh, sm, sl); h[3]=(short)sh; m[3]=(short)sm; l[3]=(short)sl;
    split3(x1.x, sh, sm, sl); h[4]=(short)sh; m[4]=(short)sm; l[4]=(short)sl;
    split3(x1.y, sh, sm, sl); h[5]=(short)sh; m[5]=(short)sm; l[5]=(short)sl;
    split3(x1.z, sh, sm, sl); h[6]=(short)sh; m[6]=(short)sm; l[6]=(short)sl;
    split3(x1.w, sh, sm, sl); h[7]=(short)sh; m[7]=(short)sm; l[7]=(short)sl;
}

// swizzled expert column for the LDS epilogue buffer (breaks write conflicts)
static __device__ __forceinline__ int swz_e(int tok, int e) {
    return e ^ (((tok >> 2) & 1) << 4);
}

// async global->LDS, 16B per lane, dest = wave-uniform base + lane*16
static __device__ __forceinline__ void glds16(const float* g, float* l)
{
    __builtin_amdgcn_global_load_lds((const __attribute__((address_space(1))) void*)g,
                                     (__attribute__((address_space(3))) void*)l,
                                     16, 0, 0);
}

// ---------------------------------------------------------------------------
// Prep kernel (round-4/5 proven, bit-identical planes): split W and pack in
// MFMA-fragment order. chunk = (ks32*12 + nt*3 + plane)*64 + lane, 16 B each,
// where ks32 = k/32. Main-kernel B loads are base + lane*16 (coalesced 1 KB).
// ---------------------------------------------------------------------------
__global__ __launch_bounds__(256)
void pack_w_kernel(const float* __restrict__ W, short* __restrict__ P)
{
    const int tid = blockIdx.x * 256 + threadIdx.x;   // 0..49151
    const int l   = tid & 63;
    int g = tid >> 6;
    const int p  = g % 3;  g /= 3;
    const int nt = g % 4;  g /= 4;
    const int ks32 = g;                               // 0..63
    const int r16 = l & 15, q = l >> 4;
    const float* src = W + (size_t)(nt * 16 + r16) * HDIM + ks32 * 32 + q * 8;
    float4 x0 = *(const float4*)src;
    float4 x1 = *(const float4*)(src + 4);
    v8s h, m, lo;
    frag3(x0, x1, h, m, lo);
    v8s outv = (p == 0) ? h : (p == 1) ? m : lo;
    *(v8s*)(P + (size_t)tid * 8) = outv;
}

// per-iteration compute: 2 ksub x (frag3 + 6 MFMA), all into one acc
#define BLOAD(ks32, p) (*(const v8s*)(pB + ((size_t)(ks32) * 12 + (p)) * 512))

#define COMPUTE(CUR, B0,B1,B2,B3,B4,B5)                                   \
    do {                                                                  \
        float4 x0 = *(const float4*)&smem[(CUR) + ap00];                  \
        float4 x1 = *(const float4*)&smem[(CUR) + ap01];                  \
        v8s Ah, Am, Al;                                                   \
        frag3(x0, x1, Ah, Am, Al);                                        \
        acc = MFMA_BF16(Ah, B0, acc, 0, 0, 0);                            \
        acc = MFMA_BF16(Ah, B1, acc, 0, 0, 0);                            \
        acc = MFMA_BF16(Am, B0, acc, 0, 0, 0);                            \
        acc = MFMA_BF16(Ah, B2, acc, 0, 0, 0);                            \
        acc = MFMA_BF16(Al, B0, acc, 0, 0, 0);                            \
        acc = MFMA_BF16(Am, B1, acc, 0, 0, 0);                            \
        float4 y0 = *(const float4*)&smem[(CUR) + ap10];                  \
        float4 y1 = *(const float4*)&smem[(CUR) + ap11];                  \
        frag3(y0, y1, Ah, Am, Al);                                        \
        acc = MFMA_BF16(Ah, B3, acc, 0, 0, 0);                            \
        acc = MFMA_BF16(Ah, B4, acc, 0, 0, 0);                            \
        acc = MFMA_BF16(Am, B3, acc, 0, 0, 0);                            \
        acc = MFMA_BF16(Ah, B5, acc, 0, 0, 0);                            \
        acc = MFMA_BF16(Al, B3, acc, 0, 0, 0);                            \
        acc = MFMA_BF16(Am, B4, acc, 0, 0, 0);                            \
    } while (0)

// ---------------------------------------------------------------------------
// Main kernel: m97-template schedule.
//  - 8 waves = (wm in {0,1} m-half x wn in {0..3} expert tile), FULL K per
//    wave -> no cross-wave reduction, acc is a single v4f.
//  - A: 32x64 fp32 tile, double-buffered (2x8 KB), staged by
//    global_load_lds (1 issue/wave/iter, linear LDS dest, chunk-swizzle
//    folded into the per-lane GLOBAL address; ds_read conflict-minimal).
//  - B: 6 packed chunks/wave/iter, register-prefetched one iter ahead.
//  - one __syncthreads per iter (compiler drains vmcnt -> glds data valid).
// ---------------------------------------------------------------------------
__global__ __launch_bounds__(512, 4)
void moe_router_mfma(const float* __restrict__ X,
                     const short* __restrict__ Pw,
                     const float* __restrict__ Bg,
                     float* __restrict__ out)
{
    __shared__ __align__(16) float smem[8192];   // A dbuf [2][32][64]; epilogue red[32][64] aliases

    const int tid  = threadIdx.x;
    const int lane = tid & 63;
    const int wv   = tid >> 6;
    const int wn   = wv & 3;               // expert tile (16 e)
    const int wm   = wv >> 2;              // m half (16 tokens)
    const int r16  = lane & 15;
    const int q    = lane >> 4;
    const int tok0 = blockIdx.x * TPB;

    // ---- A staging: wave wv covers rows wv*4..wv*4+3 (1 KB = one glds16)
    //      LDS dest linear: base + lane*16  ->  row = wv*4 + lane/16, phys chunk = lane%16
    //      swizzle phys = logical ^ (row&7) folded into the SOURCE chunk
    const int srow   = wv * 4 + (lane >> 4);
    const int schunk = (lane & 15) ^ (srow & 7);
    const float* gA  = X + (size_t)(tok0 + srow) * HDIM + schunk * 4;
    const int ldst   = wv * 256;           // float offset inside a buffer

    // ---- A fragment read offsets (floats): row = wm*16 + r16,
    //      logical chunks (ksub*8 + q*2 + {0,1}), phys = logical ^ (row&7)
    const int arow  = wm * 16 + r16;
    const int abase = arow * 64;
    const int sx    = arow & 7;
    const int ap00  = abase + (((q * 2) + 0) ^ sx) * 4;
    const int ap01  = abase + (((q * 2) + 1) ^ sx) * 4;
    const int ap10  = abase + ((8 + (q * 2) + 0) ^ sx) * 4;
    const int ap11  = abase + ((8 + (q * 2) + 1) ^ sx) * 4;

    // ---- B: packed chunk = (ks32*12 + wn*3 + p)*64 lanes
    const short* pB = Pw + (size_t)(wn * 3) * 512 + lane * 8;

    v4f acc = (v4f){0.f, 0.f, 0.f, 0.f};

    // ---- prologue: stage ks=0 into buf0, load B(ks=0)
    glds16(gA, &smem[ldst]);
    v8s Ba0 = BLOAD(0, 0), Ba1 = BLOAD(0, 1), Ba2 = BLOAD(0, 2);
    v8s Ba3 = BLOAD(1, 0), Ba4 = BLOAD(1, 1), Ba5 = BLOAD(1, 2);
    v8s Bb0, Bb1, Bb2, Bb3, Bb4, Bb5;
    __syncthreads();

    for (int ks2 = 0; ks2 < NK / 2; ++ks2) {
        // ---- even step: compute buf0 (ks = 2*ks2), stage buf1 (ks+1)
        {
            const int ksn = 2 * ks2 + 1;              // always <= 31
            glds16(gA + ksn * KSTEP, &smem[4096 + ldst]);
            const int k32 = ksn * 2;
            Bb0 = BLOAD(k32, 0); Bb1 = BLOAD(k32, 1); Bb2 = BLOAD(k32, 2);
            Bb3 = BLOAD(k32 + 1, 0); Bb4 = BLOAD(k32 + 1, 1); Bb5 = BLOAD(k32 + 1, 2);
            COMPUTE(0, Ba0, Ba1, Ba2, Ba3, Ba4, Ba5);
            __syncthreads();
        }
        // ---- odd step: compute buf1 (ks = 2*ks2+1), stage buf0 (ks+1)
        {
            const int ksn = 2 * ks2 + 2;
            if (ksn < NK) {
                glds16(gA + ksn * KSTEP, &smem[ldst]);
                const int k32 = ksn * 2;
                Ba0 = BLOAD(k32, 0); Ba1 = BLOAD(k32, 1); Ba2 = BLOAD(k32, 2);
                Ba3 = BLOAD(k32 + 1, 0); Ba4 = BLOAD(k32 + 1, 1); Ba5 = BLOAD(k32 + 1, 2);
            }
            COMPUTE(4096, Bb0, Bb1, Bb2, Bb3, Bb4, Bb5);
            __syncthreads();
        }
    }

    // ---- epilogue stage 1: scatter acc to red[32][64] (aliases A buffers;
    //      safe: last loop iteration ended with __syncthreads)
    float (*red)[NEXP] = (float (*)[NEXP])smem;
    {
        const int e = wn * 16 + r16;
#pragma unroll
        for (int r = 0; r < 4; ++r) {
            int tok = wm * 16 + q * 4 + r;       // C/D layout: col=lane&15, row=q*4+r
            red[tok][swz_e(tok, e)] = acc[r];
        }
    }
    __syncthreads();

    // ---- epilogue stage 2: 4 tokens/wave on lanes 0..3 (round-2 proven)
    // lg[] indexed by eo (STATIC -> registers); e = (eo + 16*lane) & 63
    if (lane < 4) {
        const int tk = wv * 4 + lane;
        const int t  = tok0 + tk;
        const int sh = lane << 4;                // 0,16,32,48
        float lg[NEXP];
#pragma unroll
        for (int eo = 0; eo < NEXP; ++eo) {
            int e  = (eo + sh) & (NEXP - 1);
            lg[eo] = red[tk][swz_e(tk, e)] + Bg[e];
        }
        float* outL = out + (size_t)t * NEXP;
#pragma unroll
        for (int eo = 0; eo < NEXP; eo += 4) {
            int e = (eo + sh) & (NEXP - 1);      // sh multiple of 16 -> blocks contiguous
            float4 v = make_float4(lg[eo], lg[eo+1], lg[eo+2], lg[eo+3]);
            *(float4*)(outL + e) = v;
        }
        float mx = lg[0];
#pragma unroll
        for (int eo = 1; eo < NEXP; ++eo) mx = fmaxf(mx, lg[eo]);
        float S = 0.f;
#pragma unroll
        for (int eo = 0; eo < NEXP; ++eo) { lg[eo] = expf(lg[eo] - mx); S += lg[eo]; }
#pragma unroll
        for (int eo = 0; eo < NEXP; ++eo) lg[eo] = lg[eo] / S;

        float v1 = lg[0]; int i1o = 0;
        float v2 = -1.0f; int i2o = 0;
#pragma unroll
        for (int eo = 1; eo < NEXP; ++eo) {
            float rv = lg[eo];
            bool g1 = rv > v1;
            bool g2 = rv > v2;
            float nv2 = g1 ? v1 : (g2 ? rv : v2);
            int   ni2 = g1 ? i1o : (g2 ? eo : i2o);
            v2 = nv2; i2o = ni2;
            v1 = g1 ? rv : v1;
            i1o = g1 ? eo : i1o;
        }
        const int i1 = (i1o + sh) & (NEXP - 1);
        const int i2 = (i2o + sh) & (NEXP - 1);
        float den = v1 + v2;
        float w1 = v1 / den, w2 = v2 / den;

        float* outW = out + (size_t)T_TOK * NEXP;
        float* outS = outW + (size_t)T_TOK * 2;
        float* outM = outS + (size_t)T_TOK * 2;
        outW[2*t+0] = w1;        outW[2*t+1] = w2;
        outS[2*t+0] = (float)i1; outS[2*t+1] = (float)i2;

        float* mrow = outM + (size_t)t * 2 * NEXP;
#pragma unroll
        for (int e = 0; e < NEXP; e += 4) {
            float4 a = make_float4(e+0==i1?1.f:0.f, e+1==i1?1.f:0.f,
                                   e+2==i1?1.f:0.f, e+3==i1?1.f:0.f);
            *(float4*)(mrow + e) = a;
            float4 b = make_float4(e+0==i2?1.f:0.f, e+1==i2?1.f:0.f,
                                   e+2==i2?1.f:0.f, e+3==i2?1.f:0.f);
            *(float4*)(mrow + NEXP + e) = b;
        }
    }
}

extern "C" void kernel_launch(void* const* d_in, const int* in_sizes, int n_in,
                              void* d_out, int out_size, void* d_ws, size_t ws_size,
                              hipStream_t stream)
{
    const float* X = (const float*)d_in[0];
    const float* W = (const float*)d_in[1];
    const float* B = (const float*)d_in[2];
    float* out     = (float*)d_out;

    // workspace: packed W fragments, 49152 chunks * 16 B = 768 KiB
    short* Pw = (short*)d_ws;

    hipLaunchKernelGGL(pack_w_kernel, dim3(49152 / 256), dim3(256),
                       0, stream, W, Pw);
    hipLaunchKernelGGL(moe_router_mfma, dim3(T_TOK / TPB), dim3(512),
                       0, stream, X, Pw, B, out);
}

// Round 7
// 223.979 us; speedup vs baseline: 1.1357x; 1.1357x over previous
//
#include <hip/hip_runtime.h>
#include <math.h>

constexpr int T_TOK = 16384;
constexpr int HDIM  = 2048;
constexpr int NEXP  = 64;
constexpr int TPB   = 64;            // tokens per block
constexpr int NWAVE = 8;
constexpr int KPW   = HDIM / NWAVE;  // 256 k per wave
constexpr int KSTEP = 32;
constexpr int NKS   = KPW / KSTEP;   // 8 k-steps

typedef __attribute__((ext_vector_type(8))) short v8s;   // 8 bf16 (4 VGPRs)
typedef __attribute__((ext_vector_type(4))) float v4f;   // 4 fp32 acc

#define MFMA_BF16 __builtin_amdgcn_mfma_f32_16x16x32_bf16

// Dekker-style truncation split: x = h + m + l exactly to ~24 mantissa bits.
static __device__ __forceinline__ void split3(float x, unsigned short& h,
                                              unsigned short& m, unsigned short& l)
{
    unsigned u0 = __float_as_uint(x);
    h = (unsigned short)(u0 >> 16);
    float r1 = x - __uint_as_float(u0 & 0xFFFF0000u);     // exact
    unsigned u1 = __float_as_uint(r1);
    m = (unsigned short)(u1 >> 16);
    float r2 = r1 - __uint_as_float(u1 & 0xFFFF0000u);    // exact
    l = (unsigned short)(__float_as_uint(r2) >> 16);
}

static __device__ __forceinline__ void frag3(const float4& x0, const float4& x1,
                                             v8s& h, v8s& m, v8s& l)
{
    unsigned short sh, sm, sl;
    split3(x0.x, sh, sm, sl); h[0]=(short)sh; m[0]=(short)sm; l[0]=(short)sl;
    split3(x0.y, sh, sm, sl); h[1]=(short)sh; m[1]=(short)sm; l[1]=(short)sl;
    split3(x0.z, sh, sm, sl); h[2]=(short)sh; m[2]=(short)sm; l[2]=(short)sl;
    split3(x0.w, sh, sm, sl); h[3]=(short)sh; m[3]=(short)sm; l[3]=(short)sl;
    split3(x1.x, sh, sm, sl); h[4]=(short)sh; m[4]=(short)sm; l[4]=(short)sl;
    split3(x1.y, sh, sm, sl); h[5]=(short)sh; m[5]=(short)sm; l[5]=(short)sl;
    split3(x1.z, sh, sm, sl); h[6]=(short)sh; m[6]=(short)sm; l[6]=(short)sl;
    split3(x1.w, sh, sm, sl); h[7]=(short)sh; m[7]=(short)sm; l[7]=(short)sl;
}

// swizzled expert column for the LDS reduction buffer (breaks 4-way write conflicts)
static __device__ __forceinline__ int swz_e(int tok, int e) {
    return e ^ (((tok >> 2) & 1) << 4);
}

__global__ __launch_bounds__(512, 2)
void moe_router_mfma(const float* __restrict__ X,
                     const float* __restrict__ Wg,
                     const float* __restrict__ Bg,
                     float* __restrict__ out)
{
    __shared__ float red[4][TPB][NEXP];    // 64 KiB, epilogue only

    const int tid  = threadIdx.x;
    const int lane = tid & 63;
    const int wv   = tid >> 6;             // wave id = k-slice
    const int r16  = lane & 15;
    const int q    = lane >> 4;            // quad id (k-chunk selector)
    const int tok0 = blockIdx.x * TPB;

    // A: lane reads X[tok0 + 16*mt + r16][wv*256 + ks*32 + q*8 .. +7]
    const float* pA = X  + (size_t)(tok0 + r16) * HDIM + wv * KPW + q * 8;
    // B: lane reads W[16*nt + r16][same k window]
    const float* pB = Wg + (size_t)r16 * HDIM + wv * KPW + q * 8;

    v4f acc[4][4];
#pragma unroll
    for (int mt = 0; mt < 4; ++mt)
#pragma unroll
        for (int nt = 0; nt < 4; ++nt)
            acc[mt][nt] = (v4f){0.f, 0.f, 0.f, 0.f};

    float4 a0[4], a1[4], b0[4], b1[4];
#pragma unroll
    for (int mt = 0; mt < 4; ++mt) {
        const float* p = pA + (size_t)mt * 16 * HDIM;
        a0[mt] = *(const float4*)p;
        a1[mt] = *(const float4*)(p + 4);
    }
#pragma unroll
    for (int nt = 0; nt < 4; ++nt) {
        const float* p = pB + (size_t)nt * 16 * HDIM;
        b0[nt] = *(const float4*)p;
        b1[nt] = *(const float4*)(p + 4);
    }

    // ROLLED k-loop (the single change vs the 85 us round-0 baseline).
    // Body ~700 inst ~6 KB: stays resident in the 32 KB I$ instead of
    // streaming ~45 KB of unrolled code past 8 skewed waves.
#pragma unroll 1
    for (int ks = 0; ks < NKS; ++ks) {
        // ---- split current fp32 buffers into bf16 frag triples
        v8s Ah[4], Am[4], Al[4], Bh[4], Bm[4], Bl[4];
#pragma unroll
        for (int mt = 0; mt < 4; ++mt) frag3(a0[mt], a1[mt], Ah[mt], Am[mt], Al[mt]);
#pragma unroll
        for (int nt = 0; nt < 4; ++nt) frag3(b0[nt], b1[nt], Bh[nt], Bm[nt], Bl[nt]);

        // ---- prefetch next k-step (covers HBM latency under the MFMA block)
        if (ks < NKS - 1) {
            const int off = (ks + 1) * KSTEP;
#pragma unroll
            for (int mt = 0; mt < 4; ++mt) {
                const float* p = pA + (size_t)mt * 16 * HDIM + off;
                a0[mt] = *(const float4*)p;
                a1[mt] = *(const float4*)(p + 4);
            }
#pragma unroll
            for (int nt = 0; nt < 4; ++nt) {
                const float* p = pB + (size_t)nt * 16 * HDIM + off;
                b0[nt] = *(const float4*)p;
                b1[nt] = *(const float4*)(p + 4);
            }
        }

        // ---- 6-product split GEMM: hh + hm + mh + hl + lh + mm
#pragma unroll
        for (int mt = 0; mt < 4; ++mt)
#pragma unroll
            for (int nt = 0; nt < 4; ++nt) {
                v4f a = acc[mt][nt];
                a = MFMA_BF16(Ah[mt], Bh[nt], a, 0, 0, 0);
                a = MFMA_BF16(Ah[mt], Bm[nt], a, 0, 0, 0);
                a = MFMA_BF16(Am[mt], Bh[nt], a, 0, 0, 0);
                a = MFMA_BF16(Ah[mt], Bl[nt], a, 0, 0, 0);
                a = MFMA_BF16(Al[mt], Bh[nt], a, 0, 0, 0);
                a = MFMA_BF16(Am[mt], Bm[nt], a, 0, 0, 0);
                acc[mt][nt] = a;
            }
    }

    // ---- cross-wave K reduction: 4 slots, two phases
    // C/D layout: col(expert-local) = lane&15, row(token-local) = q*4 + r
    if (wv < 4) {
#pragma unroll
        for (int mt = 0; mt < 4; ++mt)
#pragma unroll
            for (int nt = 0; nt < 4; ++nt)
#pragma unroll
                for (int r = 0; r < 4; ++r) {
                    int tok = 16 * mt + q * 4 + r;
                    int e   = 16 * nt + r16;
                    red[wv][tok][swz_e(tok, e)] = acc[mt][nt][r];
                }
    }
    __syncthreads();
    if (wv >= 4) {
#pragma unroll
        for (int mt = 0; mt < 4; ++mt)
#pragma unroll
            for (int nt = 0; nt < 4; ++nt)
#pragma unroll
                for (int r = 0; r < 4; ++r) {
                    int tok = 16 * mt + q * 4 + r;
                    int e   = 16 * nt + r16;
                    red[wv - 4][tok][swz_e(tok, e)] += acc[mt][nt][r];
                }
    }
    __syncthreads();

    // ---- epilogue: 8 tokens/wave on lanes 0..7 (round-0 proven)
    if (lane < 8) {
        const int tk = wv * 8 + lane;
        const int t  = tok0 + tk;
        float lg[NEXP];
#pragma unroll
        for (int e = 0; e < NEXP; ++e) {
            int es = swz_e(tk, e);
            lg[e] = ((red[0][tk][es] + red[1][tk][es]) +
                     (red[2][tk][es] + red[3][tk][es])) + Bg[e];
        }
        float* outL = out + (size_t)t * NEXP;
#pragma unroll
        for (int e = 0; e < NEXP; e += 4) {
            float4 v = make_float4(lg[e], lg[e+1], lg[e+2], lg[e+3]);
            *(float4*)(outL + e) = v;
        }
        float mx = lg[0];
#pragma unroll
        for (int e = 1; e < NEXP; ++e) mx = fmaxf(mx, lg[e]);
        float S = 0.f;
#pragma unroll
        for (int e = 0; e < NEXP; ++e) { lg[e] = expf(lg[e] - mx); S += lg[e]; }
#pragma unroll
        for (int e = 0; e < NEXP; ++e) lg[e] = lg[e] / S;

        float v1 = lg[0]; int i1 = 0;
        float v2 = -1.0f; int i2 = 0;
#pragma unroll
        for (int e = 1; e < NEXP; ++e) {
            float rv = lg[e];
            bool g1 = rv > v1;
            bool g2 = rv > v2;
            float nv2 = g1 ? v1 : (g2 ? rv : v2);
            int   ni2 = g1 ? i1 : (g2 ? e  : i2);
            v2 = nv2; i2 = ni2;
            v1 = g1 ? rv : v1;
            i1 = g1 ? e  : i1;
        }
        float den = v1 + v2;
        float w1 = v1 / den, w2 = v2 / den;

        float* outW = out + (size_t)T_TOK * NEXP;
        float* outS = outW + (size_t)T_TOK * 2;
        float* outM = outS + (size_t)T_TOK * 2;
        outW[2*t+0] = w1;        outW[2*t+1] = w2;
        outS[2*t+0] = (float)i1; outS[2*t+1] = (float)i2;

        float* mrow = outM + (size_t)t * 2 * NEXP;
#pragma unroll
        for (int e = 0; e < NEXP; e += 4) {
            float4 a = make_float4(e+0==i1?1.f:0.f, e+1==i1?1.f:0.f,
                                   e+2==i1?1.f:0.f, e+3==i1?1.f:0.f);
            *(float4*)(mrow + e) = a;
            float4 b = make_float4(e+0==i2?1.f:0.f, e+1==i2?1.f:0.f,
                                   e+2==i2?1.f:0.f, e+3==i2?1.f:0.f);
            *(float4*)(mrow + NEXP + e) = b;
        }
    }
}

extern "C" void kernel_launch(void* const* d_in, const int* in_sizes, int n_in,
                              void* d_out, int out_size, void* d_ws, size_t ws_size,
                              hipStream_t stream)
{
    const float* X = (const float*)d_in[0];
    const float* W = (const float*)d_in[1];
    const float* B = (const float*)d_in[2];
    float* out     = (float*)d_out;

    dim3 grid(T_TOK / TPB);   // 256 blocks, 1 per CU
    dim3 block(512);          // 8 waves
    hipLaunchKernelGGL(moe_router_mfma, grid, block, 0, stream, X, W, B, out);
}